// Round 1
// baseline (3003.464 us; speedup 1.0000x reference)
//
#include <hip/hip_runtime.h>

#define NND   8192      // N = B*NPG nodes
#define DDIM  256       // feature dim D
#define NGRP  32        // B groups
#define NPGC  256       // nodes per group
#define ZEROF 1e-8f

// ---------------- wave reduction helper ----------------
__device__ inline float wave_sum(float v) {
#pragma unroll
  for (int off = 32; off > 0; off >>= 1) v += __shfl_down(v, off, 64);
  return v;
}

// ---------------- dtype-layout detection ----------------
// Edge indices may arrive as int32 or int64 (values < 8192, so int64 high
// words are all 0).  flag=1 -> int64 layout (read raw[2*i]).
__global__ void k_detect_edges(const int* __restrict__ raw, int* __restrict__ flag) {
  __shared__ int nz;
  if (threadIdx.x == 0) nz = 0;
  __syncthreads();
  if (raw[2 * threadIdx.x + 1] != 0) atomicAdd(&nz, 1);
  __syncthreads();
  if (threadIdx.x == 0) flag[0] = (nz == 0) ? 1 : 0;
}

__global__ void k_cvt_edges(const int* __restrict__ raw, int* __restrict__ out,
                            int n2, const int* __restrict__ flag) {
  int i = blockIdx.x * 256 + threadIdx.x;
  if (i < n2) out[i] = flag[0] ? raw[2 * i] : raw[i];
}

// Masks may arrive as 1-byte bool or int32 (0/1).  flag=1 -> int32 layout.
__global__ void k_detect_mask(const unsigned char* __restrict__ raw, int* __restrict__ flag) {
  __shared__ int nz;
  if (threadIdx.x == 0) nz = 0;
  __syncthreads();
  int i = threadIdx.x * 4;
  int c = (raw[i + 1] != 0) + (raw[i + 2] != 0) + (raw[i + 3] != 0);
  if (c) atomicAdd(&nz, c);
  __syncthreads();
  if (threadIdx.x == 0) flag[0] = (nz == 0) ? 1 : 0;
}

// writes (1 - mask) as float
__global__ void k_cvt_mask(const unsigned char* __restrict__ raw, float* __restrict__ outm,
                           const int* __restrict__ flag) {
  int j = blockIdx.x * 256 + threadIdx.x;
  unsigned char v = flag[0] ? raw[4 * j] : raw[j];
  outm[j] = 1.f - (float)(v != 0);
}

// ---------------- init-A pieces ----------------
__global__ void k_node_norms(const float* __restrict__ x, float* __restrict__ nrm) {
  int node = blockIdx.x * 4 + (threadIdx.x >> 6);
  int lane = threadIdx.x & 63;
  const float4 v = *(const float4*)&x[(size_t)node * DDIM + lane * 4];
  float s = wave_sum(v.x * v.x + v.y * v.y + v.z * v.z + v.w * v.w);
  if (lane == 0) nrm[node] = sqrtf(s);
}

__global__ void k_zero(float* __restrict__ p, int n) {
  int i = blockIdx.x * blockDim.x + threadIdx.x;
  if (i < n) p[i] = 0.f;
}

// S[d] = sum_i x[i][d] / nrm[i]
__global__ void k_col_sums(const float* __restrict__ x, const float* __restrict__ nrm,
                           float* __restrict__ S) {
  int d = threadIdx.x;
  int n0 = blockIdx.x * 64;
  float s = 0.f;
  for (int i = 0; i < 64; ++i) {
    int node = n0 + i;
    float inv = 1.f / nrm[node];
    s += x[(size_t)node * DDIM + d] * inv;
  }
  atomicAdd(&S[d], s);
}

// rowsum_i = (x_i . S) / nrm_i ;  dinv_i = rsqrt(|rowsum_i| + eps)
__global__ void k_dinv(const float* __restrict__ x, const float* __restrict__ S,
                       const float* __restrict__ nrm, float* __restrict__ dinv) {
  int node = blockIdx.x * 4 + (threadIdx.x >> 6);
  int lane = threadIdx.x & 63;
  const float4 v = *(const float4*)&x[(size_t)node * DDIM + lane * 4];
  const float4 sv = *(const float4*)&S[lane * 4];
  float s = wave_sum(v.x * sv.x + v.y * sv.y + v.z * sv.z + v.w * sv.w);
  if (lane == 0) {
    float rowsum = s / nrm[node];
    dinv[node] = rsqrtf(fabsf(rowsum) + ZEROF);
  }
}

// ---------------- tiled NN GEMM: C[M][Nc] = A[M][K] @ B[K][Nc] ----------------
__global__ __launch_bounds__(256) void k_gemm_nn(const float* __restrict__ A,
                                                 const float* __restrict__ B,
                                                 float* __restrict__ C,
                                                 int M, int Ncols, int K) {
  __shared__ float As[16][68];
  __shared__ float Bs[16][68];
  const int tid = threadIdx.x;
  const int tx = tid & 15, ty = tid >> 4;
  const int row0 = blockIdx.y * 64, col0 = blockIdx.x * 64;
  float acc[4][4] = {};
  for (int k0 = 0; k0 < K; k0 += 16) {
    {
      int m = tid >> 2, kk = (tid & 3) << 2;
      const float4 a4 = *(const float4*)&A[(size_t)(row0 + m) * K + k0 + kk];
      As[kk + 0][m] = a4.x; As[kk + 1][m] = a4.y; As[kk + 2][m] = a4.z; As[kk + 3][m] = a4.w;
    }
    {
      int kk = tid >> 4, n = (tid & 15) << 2;
      const float4 b4 = *(const float4*)&B[(size_t)(k0 + kk) * Ncols + col0 + n];
      *(float4*)&Bs[kk][n] = b4;
    }
    __syncthreads();
#pragma unroll
    for (int kk = 0; kk < 16; ++kk) {
      float a[4], b[4];
      *(float4*)a = *(const float4*)&As[kk][ty << 2];
      *(float4*)b = *(const float4*)&Bs[kk][tx << 2];
#pragma unroll
      for (int i = 0; i < 4; ++i)
#pragma unroll
        for (int j = 0; j < 4; ++j)
          acc[i][j] = fmaf(a[i], b[j], acc[i][j]);
    }
    __syncthreads();
  }
#pragma unroll
  for (int i = 0; i < 4; ++i) {
    *(float4*)&C[(size_t)(row0 + (ty << 2) + i) * Ncols + col0 + (tx << 2)] =
        make_float4(acc[i][0], acc[i][1], acc[i][2], acc[i][3]);
  }
}

// ---------------- per-group NT GEMM with epilogue ----------------
// C[i][j] = sum_k P_g[i][k] * Q_g[j][k]   (P_g,Q_g = rows of group g)
// mode 0: Abuf = C * dinv_i*dinv_j / (nrm_i*nrm_j + eps)   (initial A blocks)
// mode 1: Abuf = 0.5*Abuf + 0.5*sigmoid(C)                 (A_hat update)
__global__ __launch_bounds__(256) void k_group_nt(const float* __restrict__ P,
                                                  const float* __restrict__ Q,
                                                  float* __restrict__ Abuf,
                                                  const float* __restrict__ nrm,
                                                  const float* __restrict__ dinv,
                                                  int mode) {
  __shared__ float Ps[16][68];
  __shared__ float Qs[16][68];
  const int g = blockIdx.z;
  const int tid = threadIdx.x;
  const int tx = tid & 15, ty = tid >> 4;
  const int row0 = blockIdx.y * 64, col0 = blockIdx.x * 64;
  const float* Pg = P + (size_t)g * NPGC * DDIM;
  const float* Qg = Q + (size_t)g * NPGC * DDIM;
  float acc[4][4] = {};
  for (int k0 = 0; k0 < DDIM; k0 += 16) {
    int m = tid >> 2, kk = (tid & 3) << 2;
    {
      const float4 a4 = *(const float4*)&Pg[(size_t)(row0 + m) * DDIM + k0 + kk];
      Ps[kk + 0][m] = a4.x; Ps[kk + 1][m] = a4.y; Ps[kk + 2][m] = a4.z; Ps[kk + 3][m] = a4.w;
    }
    {
      const float4 b4 = *(const float4*)&Qg[(size_t)(col0 + m) * DDIM + k0 + kk];
      Qs[kk + 0][m] = b4.x; Qs[kk + 1][m] = b4.y; Qs[kk + 2][m] = b4.z; Qs[kk + 3][m] = b4.w;
    }
    __syncthreads();
#pragma unroll
    for (int kq = 0; kq < 16; ++kq) {
      float a[4], b[4];
      *(float4*)a = *(const float4*)&Ps[kq][ty << 2];
      *(float4*)b = *(const float4*)&Qs[kq][tx << 2];
#pragma unroll
      for (int i = 0; i < 4; ++i)
#pragma unroll
        for (int j = 0; j < 4; ++j)
          acc[i][j] = fmaf(a[i], b[j], acc[i][j]);
    }
    __syncthreads();
  }
#pragma unroll
  for (int i = 0; i < 4; ++i) {
    int li = row0 + (ty << 2) + i;
    int gi = g * NPGC + li;
#pragma unroll
    for (int j = 0; j < 4; ++j) {
      int lj = col0 + (tx << 2) + j;
      int gj = g * NPGC + lj;
      size_t idx = (size_t)gi * NPGC + lj;
      if (mode == 0) {
        Abuf[idx] = acc[i][j] * dinv[gi] * dinv[gj] / (nrm[gi] * nrm[gj] + ZEROF);
      } else {
        float sg = 1.f / (1.f + expf(-acc[i][j]));
        Abuf[idx] = 0.5f * Abuf[idx] + 0.5f * sg;
      }
    }
  }
}

// ---------------- GCN pieces ----------------
// acc[n][d] = b0[d] + b1[d] + b2[d]
__global__ void k_acc_init(float* __restrict__ acc, const float* __restrict__ b3) {
  int i = blockIdx.x * 256 + threadIdx.x;
  int d = i & (DDIM - 1);
  acc[i] = b3[d] + b3[DDIM + d] + b3[2 * DDIM + d];
}

// one wave per edge: acc[dst][:] += XW[src][:] * w
__global__ void k_scatter(const float* __restrict__ XW, const int* __restrict__ ei,
                          const float* __restrict__ ew, const float* __restrict__ Abuf,
                          float* __restrict__ acc, int E_, int useA) {
  int e = blockIdx.x * 4 + (threadIdx.x >> 6);
  int lane = threadIdx.x & 63;
  if (e >= E_) return;
  int src = ei[e];
  int dst = ei[E_ + e];
  float w = useA ? Abuf[(size_t)src * NPGC + (dst & (NPGC - 1))] : ew[e];
  const float4 v = *(const float4*)&XW[(size_t)src * DDIM + lane * 4];
  float* o = &acc[(size_t)dst * DDIM + lane * 4];
  atomicAdd(o + 0, v.x * w);
  atomicAdd(o + 1, v.y * w);
  atomicAdd(o + 2, v.z * w);
  atomicAdd(o + 3, v.w * w);
}

__global__ void k_relu(const float* __restrict__ acc, float* __restrict__ H) {
  int i = blockIdx.x * 256 + threadIdx.x;
  H[i] = fmaxf(acc[i], 0.f);
}

// ---------------- final maps ----------------
// mept[n] = sum_j A[n][j]*(1-pm[g,j]) ; mpat[n] = sum_j A[n][j]*(1-em[g,j])
// (emf/pmf already hold 1-mask as float)
__global__ void k_rowmaps(const float* __restrict__ Abuf, const float* __restrict__ emf,
                          const float* __restrict__ pmf, float* __restrict__ mept,
                          float* __restrict__ mpat) {
  int node = blockIdx.x * 4 + (threadIdx.x >> 6);
  int lane = threadIdx.x & 63;
  int b = node >> 8;
  const float4 a = *(const float4*)&Abuf[(size_t)node * NPGC + lane * 4];
  int j0 = b * NPGC + lane * 4;
  const float4 pmv = *(const float4*)&pmf[j0];
  const float4 emv = *(const float4*)&emf[j0];
  float me = a.x * pmv.x + a.y * pmv.y + a.z * pmv.z + a.w * pmv.w;
  float mp = a.x * emv.x + a.y * emv.y + a.z * emv.z + a.w * emv.w;
#pragma unroll
  for (int off = 32; off > 0; off >>= 1) {
    me += __shfl_down(me, off, 64);
    mp += __shfl_down(mp, off, 64);
  }
  if (lane == 0) { mept[node] = me; mpat[node] = mp; }
}

__global__ void k_finish(const float* __restrict__ mept, const float* __restrict__ mpat,
                         float* __restrict__ out) {
  __shared__ float red[256];
  int which = blockIdx.x >> 5;
  int b = blockIdx.x & 31;
  int t = threadIdx.x;
  const float* src = which ? mpat : mept;
  float v = src[b * NPGC + t];
  red[t] = v; __syncthreads();
  for (int s = 128; s > 0; s >>= 1) { if (t < s) red[t] = fminf(red[t], red[t + s]); __syncthreads(); }
  float mn = red[0]; __syncthreads();
  red[t] = v; __syncthreads();
  for (int s = 128; s > 0; s >>= 1) { if (t < s) red[t] = fmaxf(red[t], red[t + s]); __syncthreads(); }
  float mx = red[0]; __syncthreads();
  float m = (v - mn) / (mx - mn + ZEROF);
  red[t] = m; __syncthreads();
  for (int s = 128; s > 0; s >>= 1) { if (t < s) red[t] += red[t + s]; __syncthreads(); }
  float sum = red[0];
  out[which * NND + b * NPGC + t] = m / (sum + ZEROF);
}

// ---------------- launch ----------------
extern "C" void kernel_launch(void* const* d_in, const int* in_sizes, int n_in,
                              void* d_out, int out_size, void* d_ws, size_t ws_size,
                              hipStream_t stream) {
  const float* x = (const float*)d_in[0];
  const unsigned char* em_raw = (const unsigned char*)d_in[7];
  const unsigned char* pm_raw = (const unsigned char*)d_in[8];
  const float* W  = (const float*)d_in[9];
  const float* bg = (const float*)d_in[10];
  const float* T  = (const float*)d_in[11];
  float* out = (float*)d_out;
  const int E_ = in_sizes[2];

  float* ws = (float*)d_ws;
  size_t o = 0;
  float* H    = ws + o; o += (size_t)NND * DDIM;
  float* Abuf = ws + o; o += (size_t)NND * NPGC;
  float* tmp  = ws + o; o += (size_t)NND * DDIM;
  float* acc  = ws + o; o += (size_t)NND * DDIM;
  float* nrm  = ws + o; o += NND;
  float* dinv = ws + o; o += NND;
  float* S    = ws + o; o += DDIM;
  float* mept = ws + o; o += NND;
  float* mpat = ws + o; o += NND;
  float* emf  = ws + o; o += NND;
  float* pmf  = ws + o; o += NND;
  int* edges  = (int*)(ws + o); o += (size_t)3 * 2 * E_;
  int* flags  = (int*)(ws + o); o += 16;

  int* e_arr[3] = {edges, edges + 2 * (size_t)E_, edges + 4 * (size_t)E_};
  int* flagE = flags;
  int* flagM = flags + 1;

  // normalize dtypes of edges and masks into workspace
  k_detect_edges<<<1, 256, 0, stream>>>((const int*)d_in[1], flagE);
  k_detect_mask <<<1, 256, 0, stream>>>(em_raw, flagM);
  int cvtBlocks = (2 * E_ + 255) / 256;
  k_cvt_edges<<<cvtBlocks, 256, 0, stream>>>((const int*)d_in[1], e_arr[0], 2 * E_, flagE);
  k_cvt_edges<<<cvtBlocks, 256, 0, stream>>>((const int*)d_in[3], e_arr[1], 2 * E_, flagE);
  k_cvt_edges<<<cvtBlocks, 256, 0, stream>>>((const int*)d_in[5], e_arr[2], 2 * E_, flagE);
  k_cvt_mask<<<NND / 256, 256, 0, stream>>>(em_raw, emf, flagM);
  k_cvt_mask<<<NND / 256, 256, 0, stream>>>(pm_raw, pmf, flagM);

  // initial correlation matrix (diagonal blocks only; rowsum factored)
  k_node_norms<<<NND / 4, 256, 0, stream>>>(x, nrm);
  k_zero<<<1, 256, 0, stream>>>(S, DDIM);
  k_col_sums<<<NND / 64, 256, 0, stream>>>(x, nrm, S);
  k_dinv<<<NND / 4, 256, 0, stream>>>(x, S, nrm, dinv);
  k_group_nt<<<dim3(4, 4, NGRP), 256, 0, stream>>>(x, x, Abuf, nrm, dinv, 0);

  const float* ew_arr[3] = {(const float*)d_in[2], (const float*)d_in[4], (const float*)d_in[6]};
  const float* Hcur = x;
  for (int l = 0; l < 2; ++l) {
    k_acc_init<<<NND * DDIM / 256, 256, 0, stream>>>(acc, bg + l * 3 * DDIM);
    for (int t = 0; t < 3; ++t) {
      k_gemm_nn<<<dim3(DDIM / 64, NND / 64), 256, 0, stream>>>(
          Hcur, W + ((size_t)l * 3 + t) * DDIM * DDIM, tmp, NND, DDIM, DDIM);
      k_scatter<<<E_ / 4, 256, 0, stream>>>(tmp, e_arr[t], ew_arr[t], Abuf, acc, E_, l);
    }
    k_relu<<<NND * DDIM / 256, 256, 0, stream>>>(acc, H);
    Hcur = H;
    k_gemm_nn<<<dim3(DDIM / 64, NND / 64), 256, 0, stream>>>(
        Hcur, T + (size_t)l * DDIM * DDIM, tmp, NND, DDIM, DDIM);
    k_group_nt<<<dim3(4, 4, NGRP), 256, 0, stream>>>(tmp, Hcur, Abuf, nrm, dinv, 1);
  }

  k_rowmaps<<<NND / 4, 256, 0, stream>>>(Abuf, emf, pmf, mept, mpat);
  k_finish<<<64, 256, 0, stream>>>(mept, mpat, out);
}

// Round 2
// 542.297 us; speedup vs baseline: 5.5384x; 5.5384x over previous
//
#include <hip/hip_runtime.h>

#define NND   8192      // N = B*NPG nodes
#define DDIM  256       // feature dim D
#define NGRP  32        // B groups
#define NPGC  256       // nodes per group
#define ZEROF 1e-8f

// ---------------- wave reduction helper ----------------
__device__ inline float wave_sum(float v) {
#pragma unroll
  for (int off = 32; off > 0; off >>= 1) v += __shfl_down(v, off, 64);
  return v;
}

// ---------------- dtype-layout detection ----------------
__global__ void k_detect_edges(const int* __restrict__ raw, int* __restrict__ flag) {
  __shared__ int nz;
  if (threadIdx.x == 0) nz = 0;
  __syncthreads();
  if (raw[2 * threadIdx.x + 1] != 0) atomicAdd(&nz, 1);
  __syncthreads();
  if (threadIdx.x == 0) flag[0] = (nz == 0) ? 1 : 0;
}

__global__ void k_cvt_edges(const int* __restrict__ raw, int* __restrict__ out,
                            int n2, const int* __restrict__ flag) {
  int i = blockIdx.x * 256 + threadIdx.x;
  if (i < n2) out[i] = flag[0] ? raw[2 * i] : raw[i];
}

__global__ void k_detect_mask(const unsigned char* __restrict__ raw, int* __restrict__ flag) {
  __shared__ int nz;
  if (threadIdx.x == 0) nz = 0;
  __syncthreads();
  int i = threadIdx.x * 4;
  int c = (raw[i + 1] != 0) + (raw[i + 2] != 0) + (raw[i + 3] != 0);
  if (c) atomicAdd(&nz, c);
  __syncthreads();
  if (threadIdx.x == 0) flag[0] = (nz == 0) ? 1 : 0;
}

// writes (1 - mask) as float
__global__ void k_cvt_mask(const unsigned char* __restrict__ raw, float* __restrict__ outm,
                           const int* __restrict__ flag) {
  int j = blockIdx.x * 256 + threadIdx.x;
  unsigned char v = flag[0] ? raw[4 * j] : raw[j];
  outm[j] = 1.f - (float)(v != 0);
}

// ---------------- init-A pieces ----------------
__global__ void k_node_norms(const float* __restrict__ x, float* __restrict__ nrm) {
  int node = blockIdx.x * 4 + (threadIdx.x >> 6);
  int lane = threadIdx.x & 63;
  const float4 v = *(const float4*)&x[(size_t)node * DDIM + lane * 4];
  float s = wave_sum(v.x * v.x + v.y * v.y + v.z * v.z + v.w * v.w);
  if (lane == 0) nrm[node] = sqrtf(s);
}

__global__ void k_zero(float* __restrict__ p, int n) {
  int i = blockIdx.x * blockDim.x + threadIdx.x;
  if (i < n) p[i] = 0.f;
}

// S[d] = sum_i x[i][d] / nrm[i]
__global__ void k_col_sums(const float* __restrict__ x, const float* __restrict__ nrm,
                           float* __restrict__ S) {
  int d = threadIdx.x;
  int n0 = blockIdx.x * 64;
  float s = 0.f;
  for (int i = 0; i < 64; ++i) {
    int node = n0 + i;
    float inv = 1.f / nrm[node];
    s += x[(size_t)node * DDIM + d] * inv;
  }
  atomicAdd(&S[d], s);
}

// rowsum_i = (x_i . S) / nrm_i ;  dinv_i = rsqrt(|rowsum_i| + eps)
__global__ void k_dinv(const float* __restrict__ x, const float* __restrict__ S,
                       const float* __restrict__ nrm, float* __restrict__ dinv) {
  int node = blockIdx.x * 4 + (threadIdx.x >> 6);
  int lane = threadIdx.x & 63;
  const float4 v = *(const float4*)&x[(size_t)node * DDIM + lane * 4];
  const float4 sv = *(const float4*)&S[lane * 4];
  float s = wave_sum(v.x * sv.x + v.y * sv.y + v.z * sv.z + v.w * sv.w);
  if (lane == 0) {
    float rowsum = s / nrm[node];
    dinv[node] = rsqrtf(fabsf(rowsum) + ZEROF);
  }
}

// ---------------- tiled NN GEMM: C[M][Nc] = A[M][K] @ B[K][Nc] ----------------
__global__ __launch_bounds__(256) void k_gemm_nn(const float* __restrict__ A,
                                                 const float* __restrict__ B,
                                                 float* __restrict__ C,
                                                 int M, int Ncols, int K) {
  __shared__ float As[16][68];
  __shared__ float Bs[16][68];
  const int tid = threadIdx.x;
  const int tx = tid & 15, ty = tid >> 4;
  const int row0 = blockIdx.y * 64, col0 = blockIdx.x * 64;
  float acc[4][4] = {};
  for (int k0 = 0; k0 < K; k0 += 16) {
    {
      int m = tid >> 2, kk = (tid & 3) << 2;
      const float4 a4 = *(const float4*)&A[(size_t)(row0 + m) * K + k0 + kk];
      As[kk + 0][m] = a4.x; As[kk + 1][m] = a4.y; As[kk + 2][m] = a4.z; As[kk + 3][m] = a4.w;
    }
    {
      int kk = tid >> 4, n = (tid & 15) << 2;
      const float4 b4 = *(const float4*)&B[(size_t)(k0 + kk) * Ncols + col0 + n];
      *(float4*)&Bs[kk][n] = b4;
    }
    __syncthreads();
#pragma unroll
    for (int kk = 0; kk < 16; ++kk) {
      float a[4], b[4];
      *(float4*)a = *(const float4*)&As[kk][ty << 2];
      *(float4*)b = *(const float4*)&Bs[kk][tx << 2];
#pragma unroll
      for (int i = 0; i < 4; ++i)
#pragma unroll
        for (int j = 0; j < 4; ++j)
          acc[i][j] = fmaf(a[i], b[j], acc[i][j]);
    }
    __syncthreads();
  }
#pragma unroll
  for (int i = 0; i < 4; ++i) {
    *(float4*)&C[(size_t)(row0 + (ty << 2) + i) * Ncols + col0 + (tx << 2)] =
        make_float4(acc[i][0], acc[i][1], acc[i][2], acc[i][3]);
  }
}

// ---------------- batched per-group GEMM, accumulate: acc_g += M_g @ XW_g ----------------
// M_g: 256x256 (dst_local x src_local), XW_g: 256x256, acc_g: 256x256
__global__ __launch_bounds__(256) void k_gemm_grp_acc(const float* __restrict__ Mb,
                                                      const float* __restrict__ XW,
                                                      float* __restrict__ accb) {
  __shared__ float As[16][68];
  __shared__ float Bs[16][68];
  const int g = blockIdx.z;
  const float* A = Mb + ((size_t)g << 16);
  const float* B = XW + ((size_t)g << 16);
  float* C = accb + ((size_t)g << 16);
  const int tid = threadIdx.x;
  const int tx = tid & 15, ty = tid >> 4;
  const int row0 = blockIdx.y * 64, col0 = blockIdx.x * 64;
  float acc[4][4] = {};
  for (int k0 = 0; k0 < NPGC; k0 += 16) {
    {
      int m = tid >> 2, kk = (tid & 3) << 2;
      const float4 a4 = *(const float4*)&A[(size_t)(row0 + m) * NPGC + k0 + kk];
      As[kk + 0][m] = a4.x; As[kk + 1][m] = a4.y; As[kk + 2][m] = a4.z; As[kk + 3][m] = a4.w;
    }
    {
      int kk = tid >> 4, n = (tid & 15) << 2;
      const float4 b4 = *(const float4*)&B[(size_t)(k0 + kk) * DDIM + col0 + n];
      *(float4*)&Bs[kk][n] = b4;
    }
    __syncthreads();
#pragma unroll
    for (int kk = 0; kk < 16; ++kk) {
      float a[4], b[4];
      *(float4*)a = *(const float4*)&As[kk][ty << 2];
      *(float4*)b = *(const float4*)&Bs[kk][tx << 2];
#pragma unroll
      for (int i = 0; i < 4; ++i)
#pragma unroll
        for (int j = 0; j < 4; ++j)
          acc[i][j] = fmaf(a[i], b[j], acc[i][j]);
    }
    __syncthreads();
  }
#pragma unroll
  for (int i = 0; i < 4; ++i) {
    float4* p = (float4*)&C[(size_t)(row0 + (ty << 2) + i) * DDIM + col0 + (tx << 2)];
    float4 c = *p;
    c.x += acc[i][0]; c.y += acc[i][1]; c.z += acc[i][2]; c.w += acc[i][3];
    *p = c;
  }
}

// ---------------- per-group NT GEMM with epilogue ----------------
// mode 0: Abuf = C * dinv_i*dinv_j / (nrm_i*nrm_j + eps)   (initial A blocks)
// mode 1: Abuf = 0.5*Abuf + 0.5*sigmoid(C)                 (A_hat update)
__global__ __launch_bounds__(256) void k_group_nt(const float* __restrict__ P,
                                                  const float* __restrict__ Q,
                                                  float* __restrict__ Abuf,
                                                  const float* __restrict__ nrm,
                                                  const float* __restrict__ dinv,
                                                  int mode) {
  __shared__ float Ps[16][68];
  __shared__ float Qs[16][68];
  const int g = blockIdx.z;
  const int tid = threadIdx.x;
  const int tx = tid & 15, ty = tid >> 4;
  const int row0 = blockIdx.y * 64, col0 = blockIdx.x * 64;
  const float* Pg = P + (size_t)g * NPGC * DDIM;
  const float* Qg = Q + (size_t)g * NPGC * DDIM;
  float acc[4][4] = {};
  for (int k0 = 0; k0 < DDIM; k0 += 16) {
    int m = tid >> 2, kk = (tid & 3) << 2;
    {
      const float4 a4 = *(const float4*)&Pg[(size_t)(row0 + m) * DDIM + k0 + kk];
      Ps[kk + 0][m] = a4.x; Ps[kk + 1][m] = a4.y; Ps[kk + 2][m] = a4.z; Ps[kk + 3][m] = a4.w;
    }
    {
      const float4 b4 = *(const float4*)&Qg[(size_t)(col0 + m) * DDIM + k0 + kk];
      Qs[kk + 0][m] = b4.x; Qs[kk + 1][m] = b4.y; Qs[kk + 2][m] = b4.z; Qs[kk + 3][m] = b4.w;
    }
    __syncthreads();
#pragma unroll
    for (int kq = 0; kq < 16; ++kq) {
      float a[4], b[4];
      *(float4*)a = *(const float4*)&Ps[kq][ty << 2];
      *(float4*)b = *(const float4*)&Qs[kq][tx << 2];
#pragma unroll
      for (int i = 0; i < 4; ++i)
#pragma unroll
        for (int j = 0; j < 4; ++j)
          acc[i][j] = fmaf(a[i], b[j], acc[i][j]);
    }
    __syncthreads();
  }
#pragma unroll
  for (int i = 0; i < 4; ++i) {
    int li = row0 + (ty << 2) + i;
    int gi = g * NPGC + li;
#pragma unroll
    for (int j = 0; j < 4; ++j) {
      int lj = col0 + (tx << 2) + j;
      int gj = g * NPGC + lj;
      size_t idx = (size_t)gi * NPGC + lj;
      if (mode == 0) {
        Abuf[idx] = acc[i][j] * dinv[gi] * dinv[gj] / (nrm[gi] * nrm[gj] + ZEROF);
      } else {
        float sg = 1.f / (1.f + expf(-acc[i][j]));
        Abuf[idx] = 0.5f * Abuf[idx] + 0.5f * sg;
      }
    }
  }
}

// ---------------- GCN pieces ----------------
__global__ void k_acc_init(float* __restrict__ acc, const float* __restrict__ b3) {
  int i = blockIdx.x * 256 + threadIdx.x;
  int d = i & (DDIM - 1);
  acc[i] = b3[d] + b3[DDIM + d] + b3[2 * DDIM + d];
}

// scatter edge weights into dense per-group matrices:
// M[g][dst_local][src_local] += w_e
__global__ void k_edge_to_M(const int* __restrict__ ei, const float* __restrict__ ew,
                            const float* __restrict__ Abuf, float* __restrict__ Mb,
                            int E_, int useA) {
  int e = blockIdx.x * 256 + threadIdx.x;
  if (e >= E_) return;
  int src = ei[e];
  int dst = ei[E_ + e];
  float w = useA ? Abuf[(size_t)src * NPGC + (dst & (NPGC - 1))] : ew[e];
  int g = src >> 8;
  atomicAdd(&Mb[((size_t)g << 16) + ((size_t)(dst & 255) << 8) + (src & 255)], w);
}

__global__ void k_relu(const float* __restrict__ acc, float* __restrict__ H) {
  int i = blockIdx.x * 256 + threadIdx.x;
  H[i] = fmaxf(acc[i], 0.f);
}

// ---------------- final maps ----------------
__global__ void k_rowmaps(const float* __restrict__ Abuf, const float* __restrict__ emf,
                          const float* __restrict__ pmf, float* __restrict__ mept,
                          float* __restrict__ mpat) {
  int node = blockIdx.x * 4 + (threadIdx.x >> 6);
  int lane = threadIdx.x & 63;
  int b = node >> 8;
  const float4 a = *(const float4*)&Abuf[(size_t)node * NPGC + lane * 4];
  int j0 = b * NPGC + lane * 4;
  const float4 pmv = *(const float4*)&pmf[j0];
  const float4 emv = *(const float4*)&emf[j0];
  float me = a.x * pmv.x + a.y * pmv.y + a.z * pmv.z + a.w * pmv.w;
  float mp = a.x * emv.x + a.y * emv.y + a.z * emv.z + a.w * emv.w;
#pragma unroll
  for (int off = 32; off > 0; off >>= 1) {
    me += __shfl_down(me, off, 64);
    mp += __shfl_down(mp, off, 64);
  }
  if (lane == 0) { mept[node] = me; mpat[node] = mp; }
}

__global__ void k_finish(const float* __restrict__ mept, const float* __restrict__ mpat,
                         float* __restrict__ out) {
  __shared__ float red[256];
  int which = blockIdx.x >> 5;
  int b = blockIdx.x & 31;
  int t = threadIdx.x;
  const float* src = which ? mpat : mept;
  float v = src[b * NPGC + t];
  red[t] = v; __syncthreads();
  for (int s = 128; s > 0; s >>= 1) { if (t < s) red[t] = fminf(red[t], red[t + s]); __syncthreads(); }
  float mn = red[0]; __syncthreads();
  red[t] = v; __syncthreads();
  for (int s = 128; s > 0; s >>= 1) { if (t < s) red[t] = fmaxf(red[t], red[t + s]); __syncthreads(); }
  float mx = red[0]; __syncthreads();
  float m = (v - mn) / (mx - mn + ZEROF);
  red[t] = m; __syncthreads();
  for (int s = 128; s > 0; s >>= 1) { if (t < s) red[t] += red[t + s]; __syncthreads(); }
  float sum = red[0];
  out[which * NND + b * NPGC + t] = m / (sum + ZEROF);
}

// ---------------- launch ----------------
extern "C" void kernel_launch(void* const* d_in, const int* in_sizes, int n_in,
                              void* d_out, int out_size, void* d_ws, size_t ws_size,
                              hipStream_t stream) {
  const float* x = (const float*)d_in[0];
  const unsigned char* em_raw = (const unsigned char*)d_in[7];
  const unsigned char* pm_raw = (const unsigned char*)d_in[8];
  const float* W  = (const float*)d_in[9];
  const float* bg = (const float*)d_in[10];
  const float* T  = (const float*)d_in[11];
  float* out = (float*)d_out;
  const int E_ = in_sizes[2];

  float* ws = (float*)d_ws;
  size_t o = 0;
  float* H    = ws + o; o += (size_t)NND * DDIM;
  float* Abuf = ws + o; o += (size_t)NND * NPGC;
  float* tmp  = ws + o; o += (size_t)NND * DDIM;
  float* acc  = ws + o; o += (size_t)NND * DDIM;
  float* Mb   = ws + o; o += (size_t)NGRP * NPGC * NPGC;
  float* nrm  = ws + o; o += NND;
  float* dinv = ws + o; o += NND;
  float* S    = ws + o; o += DDIM;
  float* mept = ws + o; o += NND;
  float* mpat = ws + o; o += NND;
  float* emf  = ws + o; o += NND;
  float* pmf  = ws + o; o += NND;
  int* edges  = (int*)(ws + o); o += (size_t)3 * 2 * E_;
  int* flags  = (int*)(ws + o); o += 16;

  int* e_arr[3] = {edges, edges + 2 * (size_t)E_, edges + 4 * (size_t)E_};
  int* flagE = flags;
  int* flagM = flags + 1;

  // normalize dtypes of edges and masks into workspace
  k_detect_edges<<<1, 256, 0, stream>>>((const int*)d_in[1], flagE);
  k_detect_mask <<<1, 256, 0, stream>>>(em_raw, flagM);
  int cvtBlocks = (2 * E_ + 255) / 256;
  k_cvt_edges<<<cvtBlocks, 256, 0, stream>>>((const int*)d_in[1], e_arr[0], 2 * E_, flagE);
  k_cvt_edges<<<cvtBlocks, 256, 0, stream>>>((const int*)d_in[3], e_arr[1], 2 * E_, flagE);
  k_cvt_edges<<<cvtBlocks, 256, 0, stream>>>((const int*)d_in[5], e_arr[2], 2 * E_, flagE);
  k_cvt_mask<<<NND / 256, 256, 0, stream>>>(em_raw, emf, flagM);
  k_cvt_mask<<<NND / 256, 256, 0, stream>>>(pm_raw, pmf, flagM);

  // initial correlation matrix (diagonal blocks only; rowsum factored)
  k_node_norms<<<NND / 4, 256, 0, stream>>>(x, nrm);
  k_zero<<<1, 256, 0, stream>>>(S, DDIM);
  k_col_sums<<<NND / 64, 256, 0, stream>>>(x, nrm, S);
  k_dinv<<<NND / 4, 256, 0, stream>>>(x, S, nrm, dinv);
  k_group_nt<<<dim3(4, 4, NGRP), 256, 0, stream>>>(x, x, Abuf, nrm, dinv, 0);

  const float* ew_arr[3] = {(const float*)d_in[2], (const float*)d_in[4], (const float*)d_in[6]};
  const float* Hcur = x;
  const size_t Mbytes = (size_t)NGRP * NPGC * NPGC * sizeof(float);
  for (int l = 0; l < 2; ++l) {
    k_acc_init<<<NND * DDIM / 256, 256, 0, stream>>>(acc, bg + l * 3 * DDIM);
    for (int t = 0; t < 3; ++t) {
      // XW = Hcur @ W[l][t]
      k_gemm_nn<<<dim3(DDIM / 64, NND / 64), 256, 0, stream>>>(
          Hcur, W + ((size_t)l * 3 + t) * DDIM * DDIM, tmp, NND, DDIM, DDIM);
      // dense per-group message matrix from edges
      hipMemsetAsync(Mb, 0, Mbytes, stream);
      k_edge_to_M<<<(E_ + 255) / 256, 256, 0, stream>>>(e_arr[t], ew_arr[t], Abuf, Mb, E_, l);
      // acc_g += M_g @ XW_g
      k_gemm_grp_acc<<<dim3(4, 4, NGRP), 256, 0, stream>>>(Mb, tmp, acc);
    }
    k_relu<<<NND * DDIM / 256, 256, 0, stream>>>(acc, H);
    Hcur = H;
    k_gemm_nn<<<dim3(DDIM / 64, NND / 64), 256, 0, stream>>>(
        Hcur, T + (size_t)l * DDIM * DDIM, tmp, NND, DDIM, DDIM);
    k_group_nt<<<dim3(4, 4, NGRP), 256, 0, stream>>>(tmp, Hcur, Abuf, nrm, dinv, 1);
  }

  k_rowmaps<<<NND / 4, 256, 0, stream>>>(Abuf, emf, pmf, mept, mpat);
  k_finish<<<64, 256, 0, stream>>>(mept, mpat, out);
}

// Round 3
// 500.634 us; speedup vs baseline: 5.9993x; 1.0832x over previous
//
#include <hip/hip_runtime.h>

#define NND   8192      // N = B*NPG nodes
#define DDIM  256       // feature dim D
#define NGRP  32        // B groups
#define NPGC  256       // nodes per group
#define ZEROF 1e-8f
#define LSTR  40        // LDS row stride in shorts (80 B: 8B-aligned, 2-way banks = free)

typedef __attribute__((ext_vector_type(4))) short short4v;
typedef __attribute__((ext_vector_type(8))) short short8v;
typedef __attribute__((ext_vector_type(4))) float float4v;

__device__ inline unsigned short f2bf(float x) {
  unsigned u = __float_as_uint(x);
  u += 0x7fffu + ((u >> 16) & 1u);
  return (unsigned short)(u >> 16);
}
__device__ inline float bf2f(unsigned short h) {
  return __uint_as_float((unsigned)h << 16);
}
__device__ inline void split2(float x, unsigned short& h, unsigned short& l) {
  h = f2bf(x);
  l = f2bf(x - bf2f(h));
}

// ---------------- wave reduction helper ----------------
__device__ inline float wave_sum(float v) {
#pragma unroll
  for (int off = 32; off > 0; off >>= 1) v += __shfl_down(v, off, 64);
  return v;
}

// ---------------- dtype-layout detection ----------------
__global__ void k_detect_edges(const int* __restrict__ raw, int* __restrict__ flag) {
  __shared__ int nz;
  if (threadIdx.x == 0) nz = 0;
  __syncthreads();
  if (raw[2 * threadIdx.x + 1] != 0) atomicAdd(&nz, 1);
  __syncthreads();
  if (threadIdx.x == 0) flag[0] = (nz == 0) ? 1 : 0;
}

__global__ void k_cvt_edges(const int* __restrict__ raw, int* __restrict__ out,
                            int n2, const int* __restrict__ flag) {
  int i = blockIdx.x * 256 + threadIdx.x;
  if (i < n2) out[i] = flag[0] ? raw[2 * i] : raw[i];
}

__global__ void k_detect_mask(const unsigned char* __restrict__ raw, int* __restrict__ flag) {
  __shared__ int nz;
  if (threadIdx.x == 0) nz = 0;
  __syncthreads();
  int i = threadIdx.x * 4;
  int c = (raw[i + 1] != 0) + (raw[i + 2] != 0) + (raw[i + 3] != 0);
  if (c) atomicAdd(&nz, c);
  __syncthreads();
  if (threadIdx.x == 0) flag[0] = (nz == 0) ? 1 : 0;
}

__global__ void k_cvt_mask(const unsigned char* __restrict__ raw, float* __restrict__ outm,
                           const int* __restrict__ flag) {
  int j = blockIdx.x * 256 + threadIdx.x;
  unsigned char v = flag[0] ? raw[4 * j] : raw[j];
  outm[j] = 1.f - (float)(v != 0);
}

// ---------------- init-A pieces ----------------
__global__ void k_node_norms(const float* __restrict__ x, float* __restrict__ nrm) {
  int node = blockIdx.x * 4 + (threadIdx.x >> 6);
  int lane = threadIdx.x & 63;
  const float4 v = *(const float4*)&x[(size_t)node * DDIM + lane * 4];
  float s = wave_sum(v.x * v.x + v.y * v.y + v.z * v.z + v.w * v.w);
  if (lane == 0) nrm[node] = sqrtf(s);
}

__global__ void k_zero(float* __restrict__ p, int n) {
  int i = blockIdx.x * blockDim.x + threadIdx.x;
  if (i < n) p[i] = 0.f;
}

__global__ void k_col_sums(const float* __restrict__ x, const float* __restrict__ nrm,
                           float* __restrict__ S) {
  int d = threadIdx.x;
  int n0 = blockIdx.x * 64;
  float s = 0.f;
  for (int i = 0; i < 64; ++i) {
    int node = n0 + i;
    float inv = 1.f / nrm[node];
    s += x[(size_t)node * DDIM + d] * inv;
  }
  atomicAdd(&S[d], s);
}

__global__ void k_dinv(const float* __restrict__ x, const float* __restrict__ S,
                       const float* __restrict__ nrm, float* __restrict__ dinv) {
  int node = blockIdx.x * 4 + (threadIdx.x >> 6);
  int lane = threadIdx.x & 63;
  const float4 v = *(const float4*)&x[(size_t)node * DDIM + lane * 4];
  const float4 sv = *(const float4*)&S[lane * 4];
  float s = wave_sum(v.x * sv.x + v.y * sv.y + v.z * sv.z + v.w * sv.w);
  if (lane == 0) {
    float rowsum = s / nrm[node];
    dinv[node] = rsqrtf(fabsf(rowsum) + ZEROF);
  }
}

// ---------------- 32x33-tiled transpose of the 8 weight matrices ----------------
// Wt[m][n][k] = src_m[k][n];  m<6 -> W_gcn, m>=6 -> T_dyn
__global__ void k_transpose8(const float* __restrict__ W, const float* __restrict__ T,
                             float* __restrict__ Wt) {
  __shared__ float tile[32][33];
  int mat = blockIdx.z;
  const float* src = (mat < 6) ? (W + (size_t)mat * 65536) : (T + (size_t)(mat - 6) * 65536);
  float* dst = Wt + (size_t)mat * 65536;
  int k0 = blockIdx.y * 32, n0 = blockIdx.x * 32;
  int r = threadIdx.x >> 3, c4 = (threadIdx.x & 7) * 4;
  const float4 v = *(const float4*)&src[(size_t)(k0 + r) * 256 + n0 + c4];
  tile[r][c4 + 0] = v.x; tile[r][c4 + 1] = v.y; tile[r][c4 + 2] = v.z; tile[r][c4 + 3] = v.w;
  __syncthreads();
  float4 o;
  o.x = tile[c4 + 0][r]; o.y = tile[c4 + 1][r]; o.z = tile[c4 + 2][r]; o.w = tile[c4 + 3][r];
  *(float4*)&dst[(size_t)(n0 + r) * 256 + k0 + c4] = o;
}

// ---------------- unified split-bf16 MFMA GEMM ----------------
// C[row][col] (+)= sum_k P[row][k] * B[k][col],  K = 256, per-group rows.
//   P: row-major [8192][256], row = g*256 + by*64 + m
//   B: if !BT, Q is row-major [n][k] (NT form, A-pattern load), n = bx*128 + c,
//      at group offset g*qgstride.  if BT, Q is row-major [k][n] (transposed on stage).
// MODE 0: C = P.B          (XW = H@W; Q = Wt shared, qgstride = 0)
// MODE 1: C += P.B         (acc += M@XW; BT=true, Q = tmp)
// MODE 2: Abuf = (P.B) * dinv_i*dinv_j / (nrm_i*nrm_j + eps)   (init A; P=Q=x)
// MODE 3: Abuf = 0.5*Abuf + 0.5*sigmoid(P.B)                   (A update; P=tmp, Q=H)
// Split bf16x3: x = hi + lo; x*y ~= xh*yh + xh*yl + xl*yh  (rel err ~2^-17)
template<int MODE, bool BT>
__global__ __launch_bounds__(256) void k_mfma(const float* __restrict__ P,
                                              const float* __restrict__ Q,
                                              float* __restrict__ C,
                                              const float* __restrict__ nrm,
                                              const float* __restrict__ dinv,
                                              int qgstride) {
  __shared__ unsigned short Ah[64][LSTR], Al[64][LSTR];
  __shared__ unsigned short Bh[128][LSTR], Bl[128][LSTR];
  const int tid = threadIdx.x;
  const int g = blockIdx.z;
  const int row0 = g * 256 + blockIdx.y * 64;   // global P/C row base
  const int col0 = blockIdx.x * 128;            // C col base / Q row base (local)
  const size_t qoff = (size_t)g * (size_t)qgstride;

  const int w = tid >> 6, lane = tid & 63;
  const int lm = lane & 15, lq = lane >> 4;
  const int wr = (w >> 1) * 32, wc = (w & 1) * 64;

  float4v acc[2][4];
#pragma unroll
  for (int i = 0; i < 2; ++i)
#pragma unroll
    for (int j = 0; j < 4; ++j) acc[i][j] = (float4v)0.f;

  for (int k0 = 0; k0 < 256; k0 += 32) {
    if (k0) __syncthreads();
    // ---- stage A tile: 64 rows x 32 k, split to hi/lo bf16 ----
    {
      int m = tid >> 3, kq = (tid & 7) * 4;
#pragma unroll
      for (int p = 0; p < 2; ++p, m += 32) {
        const float4 v = *(const float4*)&P[(size_t)(row0 + m) * 256 + k0 + kq];
        ushort4 h, l;
        split2(v.x, h.x, l.x); split2(v.y, h.y, l.y);
        split2(v.z, h.z, l.z); split2(v.w, h.w, l.w);
        *(ushort4*)&Ah[m][kq] = h;
        *(ushort4*)&Al[m][kq] = l;
      }
    }
    // ---- stage B tile: 128 n x 32 k ----
    if (!BT) {
      int n = tid >> 3, kq = (tid & 7) * 4;
#pragma unroll
      for (int p = 0; p < 4; ++p, n += 32) {
        const float4 v = *(const float4*)&Q[qoff + (size_t)(col0 + n) * 256 + k0 + kq];
        ushort4 h, l;
        split2(v.x, h.x, l.x); split2(v.y, h.y, l.y);
        split2(v.z, h.z, l.z); split2(v.w, h.w, l.w);
        *(ushort4*)&Bh[n][kq] = h;
        *(ushort4*)&Bl[n][kq] = l;
      }
    } else {
      int k = tid >> 5, nq = (tid & 31) * 4;
#pragma unroll
      for (int p = 0; p < 4; ++p, k += 8) {
        const float4 v = *(const float4*)&Q[qoff + (size_t)(k0 + k) * 256 + col0 + nq];
        unsigned short h, l;
        split2(v.x, h, l); Bh[nq + 0][k] = h; Bl[nq + 0][k] = l;
        split2(v.y, h, l); Bh[nq + 1][k] = h; Bl[nq + 1][k] = l;
        split2(v.z, h, l); Bh[nq + 2][k] = h; Bl[nq + 2][k] = l;
        split2(v.w, h, l); Bh[nq + 3][k] = h; Bl[nq + 3][k] = l;
      }
    }
    __syncthreads();
    // ---- fragments: A[m=lane&15][k=lq*8+j], B same pattern (NT) ----
    short8v ah[2], al[2], bh[4], bl[4];
#pragma unroll
    for (int i = 0; i < 2; ++i) {
      int r = wr + i * 16 + lm;
      short4v h0 = *(const short4v*)&Ah[r][lq * 8];
      short4v h1 = *(const short4v*)&Ah[r][lq * 8 + 4];
      ah[i] = __builtin_shufflevector(h0, h1, 0, 1, 2, 3, 4, 5, 6, 7);
      short4v l0 = *(const short4v*)&Al[r][lq * 8];
      short4v l1 = *(const short4v*)&Al[r][lq * 8 + 4];
      al[i] = __builtin_shufflevector(l0, l1, 0, 1, 2, 3, 4, 5, 6, 7);
    }
#pragma unroll
    for (int j = 0; j < 4; ++j) {
      int r = wc + j * 16 + lm;
      short4v h0 = *(const short4v*)&Bh[r][lq * 8];
      short4v h1 = *(const short4v*)&Bh[r][lq * 8 + 4];
      bh[j] = __builtin_shufflevector(h0, h1, 0, 1, 2, 3, 4, 5, 6, 7);
      short4v l0 = *(const short4v*)&Bl[r][lq * 8];
      short4v l1 = *(const short4v*)&Bl[r][lq * 8 + 4];
      bl[j] = __builtin_shufflevector(l0, l1, 0, 1, 2, 3, 4, 5, 6, 7);
    }
#pragma unroll
    for (int i = 0; i < 2; ++i)
#pragma unroll
      for (int j = 0; j < 4; ++j) {
        acc[i][j] = __builtin_amdgcn_mfma_f32_16x16x32_bf16(ah[i], bh[j], acc[i][j], 0, 0, 0);
        acc[i][j] = __builtin_amdgcn_mfma_f32_16x16x32_bf16(ah[i], bl[j], acc[i][j], 0, 0, 0);
        acc[i][j] = __builtin_amdgcn_mfma_f32_16x16x32_bf16(al[i], bh[j], acc[i][j], 0, 0, 0);
      }
  }
  // ---- epilogue: C/D frag layout col=lane&15, row=lq*4+reg ----
#pragma unroll
  for (int i = 0; i < 2; ++i) {
#pragma unroll
    for (int r = 0; r < 4; ++r) {
      int grow = row0 + wr + i * 16 + lq * 4 + r;
      float di = 0.f, ni = 0.f;
      if (MODE == 2) { di = dinv[grow]; ni = nrm[grow]; }
#pragma unroll
      for (int j = 0; j < 4; ++j) {
        int gcol = col0 + wc + j * 16 + lm;
        size_t ci = (size_t)grow * 256 + gcol;
        float v = acc[i][j][r];
        if (MODE == 0) {
          C[ci] = v;
        } else if (MODE == 1) {
          C[ci] += v;
        } else if (MODE == 2) {
          int gj = g * 256 + gcol;
          C[ci] = v * di * dinv[gj] / (ni * nrm[gj] + ZEROF);
        } else {
          C[ci] = 0.5f * C[ci] + 0.5f * (1.f / (1.f + expf(-v)));
        }
      }
    }
  }
}

// ---------------- GCN pieces ----------------
__global__ void k_acc_init(float* __restrict__ acc, const float* __restrict__ b3) {
  int i = blockIdx.x * 256 + threadIdx.x;
  int d = i & (DDIM - 1);
  acc[i] = b3[d] + b3[DDIM + d] + b3[2 * DDIM + d];
}

// M[g][dst_local][src_local] += w_e
__global__ void k_edge_to_M(const int* __restrict__ ei, const float* __restrict__ ew,
                            const float* __restrict__ Abuf, float* __restrict__ Mb,
                            int E_, int useA) {
  int e = blockIdx.x * 256 + threadIdx.x;
  if (e >= E_) return;
  int src = ei[e];
  int dst = ei[E_ + e];
  float w = useA ? Abuf[(size_t)src * NPGC + (dst & (NPGC - 1))] : ew[e];
  int g = src >> 8;
  atomicAdd(&Mb[((size_t)g << 16) + ((size_t)(dst & 255) << 8) + (src & 255)], w);
}

__global__ void k_relu(const float* __restrict__ acc, float* __restrict__ H) {
  int i = blockIdx.x * 256 + threadIdx.x;
  H[i] = fmaxf(acc[i], 0.f);
}

// ---------------- final maps ----------------
__global__ void k_rowmaps(const float* __restrict__ Abuf, const float* __restrict__ emf,
                          const float* __restrict__ pmf, float* __restrict__ mept,
                          float* __restrict__ mpat) {
  int node = blockIdx.x * 4 + (threadIdx.x >> 6);
  int lane = threadIdx.x & 63;
  int b = node >> 8;
  const float4 a = *(const float4*)&Abuf[(size_t)node * NPGC + lane * 4];
  int j0 = b * NPGC + lane * 4;
  const float4 pmv = *(const float4*)&pmf[j0];
  const float4 emv = *(const float4*)&emf[j0];
  float me = a.x * pmv.x + a.y * pmv.y + a.z * pmv.z + a.w * pmv.w;
  float mp = a.x * emv.x + a.y * emv.y + a.z * emv.z + a.w * emv.w;
#pragma unroll
  for (int off = 32; off > 0; off >>= 1) {
    me += __shfl_down(me, off, 64);
    mp += __shfl_down(mp, off, 64);
  }
  if (lane == 0) { mept[node] = me; mpat[node] = mp; }
}

__global__ void k_finish(const float* __restrict__ mept, const float* __restrict__ mpat,
                         float* __restrict__ out) {
  __shared__ float red[256];
  int which = blockIdx.x >> 5;
  int b = blockIdx.x & 31;
  int t = threadIdx.x;
  const float* src = which ? mpat : mept;
  float v = src[b * NPGC + t];
  red[t] = v; __syncthreads();
  for (int s = 128; s > 0; s >>= 1) { if (t < s) red[t] = fminf(red[t], red[t + s]); __syncthreads(); }
  float mn = red[0]; __syncthreads();
  red[t] = v; __syncthreads();
  for (int s = 128; s > 0; s >>= 1) { if (t < s) red[t] = fmaxf(red[t], red[t + s]); __syncthreads(); }
  float mx = red[0]; __syncthreads();
  float m = (v - mn) / (mx - mn + ZEROF);
  red[t] = m; __syncthreads();
  for (int s = 128; s > 0; s >>= 1) { if (t < s) red[t] += red[t + s]; __syncthreads(); }
  float sum = red[0];
  out[which * NND + b * NPGC + t] = m / (sum + ZEROF);
}

// ---------------- launch ----------------
extern "C" void kernel_launch(void* const* d_in, const int* in_sizes, int n_in,
                              void* d_out, int out_size, void* d_ws, size_t ws_size,
                              hipStream_t stream) {
  const float* x = (const float*)d_in[0];
  const unsigned char* em_raw = (const unsigned char*)d_in[7];
  const unsigned char* pm_raw = (const unsigned char*)d_in[8];
  const float* W  = (const float*)d_in[9];
  const float* bg = (const float*)d_in[10];
  const float* T  = (const float*)d_in[11];
  float* out = (float*)d_out;
  const int E_ = in_sizes[2];

  float* ws = (float*)d_ws;
  size_t o = 0;
  float* H    = ws + o; o += (size_t)NND * DDIM;
  float* Abuf = ws + o; o += (size_t)NND * NPGC;
  float* tmp  = ws + o; o += (size_t)NND * DDIM;
  float* acc  = ws + o; o += (size_t)NND * DDIM;
  float* Mb   = ws + o; o += (size_t)NGRP * NPGC * NPGC;
  float* Wt   = ws + o; o += (size_t)8 * DDIM * DDIM;
  float* nrm  = ws + o; o += NND;
  float* dinv = ws + o; o += NND;
  float* S    = ws + o; o += DDIM;
  float* mept = ws + o; o += NND;
  float* mpat = ws + o; o += NND;
  float* emf  = ws + o; o += NND;
  float* pmf  = ws + o; o += NND;
  int* edges  = (int*)(ws + o); o += (size_t)3 * 2 * E_;
  int* flags  = (int*)(ws + o); o += 16;

  int* e_arr[3] = {edges, edges + 2 * (size_t)E_, edges + 4 * (size_t)E_};
  int* flagE = flags;
  int* flagM = flags + 1;

  // normalize dtypes of edges and masks into workspace
  k_detect_edges<<<1, 256, 0, stream>>>((const int*)d_in[1], flagE);
  k_detect_mask <<<1, 256, 0, stream>>>(em_raw, flagM);
  int cvtBlocks = (2 * E_ + 255) / 256;
  k_cvt_edges<<<cvtBlocks, 256, 0, stream>>>((const int*)d_in[1], e_arr[0], 2 * E_, flagE);
  k_cvt_edges<<<cvtBlocks, 256, 0, stream>>>((const int*)d_in[3], e_arr[1], 2 * E_, flagE);
  k_cvt_edges<<<cvtBlocks, 256, 0, stream>>>((const int*)d_in[5], e_arr[2], 2 * E_, flagE);
  k_cvt_mask<<<NND / 256, 256, 0, stream>>>(em_raw, emf, flagM);
  k_cvt_mask<<<NND / 256, 256, 0, stream>>>(pm_raw, pmf, flagM);

  // weight transposes (Wt[m][n][k])
  k_transpose8<<<dim3(8, 8, 8), 256, 0, stream>>>(W, T, Wt);

  // initial correlation matrix (diagonal blocks only; rowsum factored)
  k_node_norms<<<NND / 4, 256, 0, stream>>>(x, nrm);
  k_zero<<<1, 256, 0, stream>>>(S, DDIM);
  k_col_sums<<<NND / 64, 256, 0, stream>>>(x, nrm, S);
  k_dinv<<<NND / 4, 256, 0, stream>>>(x, S, nrm, dinv);

  const dim3 gg(2, 4, NGRP);
  k_mfma<2, false><<<gg, 256, 0, stream>>>(x, x, Abuf, nrm, dinv, NPGC * DDIM);

  const float* ew_arr[3] = {(const float*)d_in[2], (const float*)d_in[4], (const float*)d_in[6]};
  const float* Hcur = x;
  const size_t Mbytes = (size_t)NGRP * NPGC * NPGC * sizeof(float);
  for (int l = 0; l < 2; ++l) {
    k_acc_init<<<NND * DDIM / 256, 256, 0, stream>>>(acc, bg + l * 3 * DDIM);
    for (int t = 0; t < 3; ++t) {
      // XW = Hcur @ W[l][t]  (Q = Wt, shared across groups)
      k_mfma<0, false><<<gg, 256, 0, stream>>>(
          Hcur, Wt + ((size_t)l * 3 + t) * DDIM * DDIM, tmp, nullptr, nullptr, 0);
      // dense per-group message matrix from edges
      hipMemsetAsync(Mb, 0, Mbytes, stream);
      k_edge_to_M<<<(E_ + 255) / 256, 256, 0, stream>>>(e_arr[t], ew_arr[t], Abuf, Mb, E_, l);
      // acc_g += M_g @ XW_g   (B = tmp, [k][n] layout -> transpose-stage)
      k_mfma<1, true><<<gg, 256, 0, stream>>>(Mb, tmp, acc, nullptr, nullptr, NPGC * DDIM);
    }
    k_relu<<<NND * DDIM / 256, 256, 0, stream>>>(acc, H);
    Hcur = H;
    // tmp = H @ T[l]
    k_mfma<0, false><<<gg, 256, 0, stream>>>(
        Hcur, Wt + (size_t)(6 + l) * DDIM * DDIM, tmp, nullptr, nullptr, 0);
    // A = 0.5 A + 0.5 sigmoid(tmp @ H^T)
    k_mfma<3, false><<<gg, 256, 0, stream>>>(tmp, Hcur, Abuf, nullptr, nullptr, NPGC * DDIM);
  }

  k_rowmaps<<<NND / 4, 256, 0, stream>>>(Abuf, emf, pmf, mept, mpat);
  k_finish<<<64, 256, 0, stream>>>(mept, mpat, out);
}

// Round 4
// 386.892 us; speedup vs baseline: 7.7630x; 1.2940x over previous
//
#include <hip/hip_runtime.h>

#define NND   8192
#define DDIM  256
#define NGRP  32
#define NPGC  256
#define ZEROF 1e-8f
#define LSTR  40   // LDS row stride in u16 (80 B = 16B-aligned, 2-way bank pattern = free)

typedef unsigned short u16;
typedef __attribute__((ext_vector_type(8))) short short8v;
typedef __attribute__((ext_vector_type(4))) float float4v;

__device__ inline u16 f2bf(float x) {
  unsigned u = __float_as_uint(x);
  u += 0x7fffu + ((u >> 16) & 1u);
  return (u16)(u >> 16);
}
__device__ inline float bf2f(u16 h) { return __uint_as_float((unsigned)h << 16); }
__device__ inline void split2(float x, u16& h, u16& l) {
  h = f2bf(x);
  l = f2bf(x - bf2f(h));
}

__device__ inline float wave_sum(float v) {
#pragma unroll
  for (int off = 32; off > 0; off >>= 1) v += __shfl_down(v, off, 64);
  return v;
}

// ---------------- detection (+ S zero) ----------------
__global__ void k_detect(const int* __restrict__ eraw, const unsigned char* __restrict__ mraw,
                         int* __restrict__ flags, float* __restrict__ S) {
  __shared__ int nzE, nzM;
  if (threadIdx.x == 0) { nzE = 0; nzM = 0; }
  __syncthreads();
  if (eraw[2 * threadIdx.x + 1] != 0) atomicAdd(&nzE, 1);
  int i4 = threadIdx.x * 4;
  int c = (mraw[i4 + 1] != 0) + (mraw[i4 + 2] != 0) + (mraw[i4 + 3] != 0);
  if (c) atomicAdd(&nzM, c);
  S[threadIdx.x] = 0.f;
  __syncthreads();
  if (threadIdx.x == 0) { flags[0] = (nzE == 0); flags[1] = (nzM == 0); }
}

// ---------------- fused dtype conversion: 3 edge arrays + 2 masks ----------------
__global__ void k_cvt_all(const int* __restrict__ e0, const int* __restrict__ e1,
                          const int* __restrict__ e2, const unsigned char* __restrict__ m0,
                          const unsigned char* __restrict__ m1, int* __restrict__ eo,
                          float* __restrict__ emf, float* __restrict__ pmf,
                          int E2, const int* __restrict__ flags) {
  int i = blockIdx.x * 256 + threadIdx.x;
  int fE = flags[0], fM = flags[1];
  if (i < E2) {
    eo[i] = fE ? e0[2 * i] : e0[i];
  } else if (i < 2 * E2) {
    int j = i - E2; eo[E2 + j] = fE ? e1[2 * j] : e1[j];
  } else if (i < 3 * E2) {
    int j = i - 2 * E2; eo[2 * E2 + j] = fE ? e2[2 * j] : e2[j];
  } else if (i < 3 * E2 + NND) {
    int j = i - 3 * E2; unsigned char v = fM ? m0[4 * j] : m0[j];
    emf[j] = 1.f - (float)(v != 0);
  } else if (i < 3 * E2 + 2 * NND) {
    int j = i - 3 * E2 - NND; unsigned char v = fM ? m1[4 * j] : m1[j];
    pmf[j] = 1.f - (float)(v != 0);
  }
}

// ---------------- transpose + bf16-split the 8 weight matrices ----------------
__global__ void k_transpose8(const float* __restrict__ W, const float* __restrict__ T,
                             u16* __restrict__ Wth, u16* __restrict__ Wtl) {
  __shared__ float tile[32][33];
  int mat = blockIdx.z;
  const float* src = (mat < 6) ? (W + (size_t)mat * 65536) : (T + (size_t)(mat - 6) * 65536);
  int k0 = blockIdx.y * 32, n0 = blockIdx.x * 32;
  int r = threadIdx.x >> 3, c4 = (threadIdx.x & 7) * 4;
  const float4 v = *(const float4*)&src[(size_t)(k0 + r) * 256 + n0 + c4];
  tile[r][c4 + 0] = v.x; tile[r][c4 + 1] = v.y; tile[r][c4 + 2] = v.z; tile[r][c4 + 3] = v.w;
  __syncthreads();
  float o[4] = {tile[c4 + 0][r], tile[c4 + 1][r], tile[c4 + 2][r], tile[c4 + 3][r]};
  u16 hh[4], ll[4];
#pragma unroll
  for (int q = 0; q < 4; ++q) split2(o[q], hh[q], ll[q]);
  size_t off = (size_t)mat * 65536 + (size_t)(n0 + r) * 256 + k0 + c4;
  *(ushort4*)&Wth[off] = *(ushort4*)hh;
  *(ushort4*)&Wtl[off] = *(ushort4*)ll;
}

// ---------------- x -> hi/lo bf16 ----------------
__global__ void k_split_x(const float* __restrict__ x, u16* __restrict__ Hh,
                          u16* __restrict__ Hl) {
  size_t i = ((size_t)blockIdx.x * 256 + threadIdx.x) * 8;
  float4 a = *(const float4*)&x[i];
  float4 b = *(const float4*)&x[i + 4];
  u16 hh[8], ll[8];
  split2(a.x, hh[0], ll[0]); split2(a.y, hh[1], ll[1]);
  split2(a.z, hh[2], ll[2]); split2(a.w, hh[3], ll[3]);
  split2(b.x, hh[4], ll[4]); split2(b.y, hh[5], ll[5]);
  split2(b.z, hh[6], ll[6]); split2(b.w, hh[7], ll[7]);
  *(ushort4*)&Hh[i] = *(ushort4*)hh; *(ushort4*)&Hh[i + 4] = *(ushort4*)(hh + 4);
  *(ushort4*)&Hl[i] = *(ushort4*)ll; *(ushort4*)&Hl[i + 4] = *(ushort4*)(ll + 4);
}

// ---------------- node norms + column sums (fused) ----------------
__global__ void k_norms_colsum(const float* __restrict__ x, float* __restrict__ nrm,
                               float* __restrict__ S) {
  __shared__ float inv[64];
  int n0 = blockIdx.x * 64;
  int tid = threadIdx.x, w = tid >> 6, lane = tid & 63;
  for (int it = 0; it < 16; ++it) {
    int nl = it * 4 + w;
    const float4 v = *(const float4*)&x[(size_t)(n0 + nl) * 256 + lane * 4];
    float s = wave_sum(v.x * v.x + v.y * v.y + v.z * v.z + v.w * v.w);
    if (lane == 0) { float nr = sqrtf(s); nrm[n0 + nl] = nr; inv[nl] = 1.f / nr; }
  }
  __syncthreads();
  float s = 0.f;
  for (int i = 0; i < 64; ++i) s += x[(size_t)(n0 + i) * 256 + tid] * inv[i];
  atomicAdd(&S[tid], s);
}

__global__ void k_dinv(const float* __restrict__ x, const float* __restrict__ S,
                       const float* __restrict__ nrm, float* __restrict__ dinv) {
  int node = blockIdx.x * 4 + (threadIdx.x >> 6);
  int lane = threadIdx.x & 63;
  const float4 v = *(const float4*)&x[(size_t)node * 256 + lane * 4];
  const float4 sv = *(const float4*)&S[lane * 4];
  float s = wave_sum(v.x * sv.x + v.y * sv.y + v.z * sv.z + v.w * sv.w);
  if (lane == 0) {
    float rowsum = s / nrm[node];
    dinv[node] = rsqrtf(fabsf(rowsum) + ZEROF);
  }
}

// ---------------- fused edge scatter (all 3 types) ----------------
__global__ void k_edge3(const int* __restrict__ edges, const float* __restrict__ ew0,
                        const float* __restrict__ ew1, const float* __restrict__ ew2,
                        const float* __restrict__ Abuf, float* __restrict__ Mb3,
                        int E_, int useA) {
  int i = blockIdx.x * 256 + threadIdx.x;
  if (i >= 3 * E_) return;
  int t = i / E_;
  int e = i - t * E_;
  const int* ei = edges + (size_t)t * 2 * E_;
  int src = ei[e], dst = ei[E_ + e];
  float w;
  if (useA) w = Abuf[(size_t)src * 256 + (dst & 255)];
  else      w = (t == 0 ? ew0 : (t == 1 ? ew1 : ew2))[e];
  int g = src >> 8;
  atomicAdd(&Mb3[(((size_t)g * 3 + t) << 16) + ((size_t)(dst & 255) << 8) + (src & 255)], w);
}

// ---------------- unified split-bf16 MFMA GEMM (register-prefetch pipelined) ----------------
// All modes: C-tile 64 (rows) x 128 (cols), 4 waves of 32x64, 16x16x32 bf16 MFMA,
// split-bf16x3 (hi*hi + hi*lo + lo*hi).
// MODE 0: XWT[c][node] = (H @ Wcat)[node][c]     A=Hh/Hl, B=Wth(l) NT, grid(6,128)
// MODE 1: H = relu(bias + sum_t M_t @ XW_t)      A=XWT rows(t*256+d), B=M fp32, grid(2,4,32)
// MODE 2: Abuf = (x.x^T) * dinv_i dinv_j/(nrm_i nrm_j+eps)  A=B=Hh(x), grid(2,4,32)
// MODE 3: Abuf = 0.5 Abuf + 0.5 sigmoid(tmp.H^T) A=tmph, B=Hh, grid(2,4,32)
// MODE 4: tmp = H @ T                            A=Hh, B=Wth(6+l) NT, grid(2,128)
#define LOAD_REGS(tt, kk)                                                                  \
  {                                                                                        \
    int m_ = tid >> 2, kq_ = (tid & 3) * 8;                                                \
    size_t aoff_;                                                                          \
    if (MODE == 1)                                                                         \
      aoff_ = (size_t)((tt) * 256 + by * 64 + m_) * 8192 + (size_t)(g * 256 + (kk) + kq_); \
    else if (MODE == 2 || MODE == 3)                                                       \
      aoff_ = (size_t)(g * 256 + by * 64 + m_) * 256 + (kk) + kq_;                         \
    else                                                                                   \
      aoff_ = (size_t)(by * 64 + m_) * 256 + (kk) + kq_;                                   \
    rAh = *(const short8v*)&Ah_g[aoff_];                                                   \
    rAl = *(const short8v*)&Al_g[aoff_];                                                   \
    if (MODE == 1) {                                                                       \
      int n_ = tid >> 1, kq2_ = (tid & 1) * 16;                                            \
      const float* pb_ = Bfp + (((size_t)g * 3 + (tt)) << 16) +                            \
                         (size_t)(col0 + n_) * 256 + (kk) + kq2_;                          \
      rBf[0] = *(const float4*)pb_;       rBf[1] = *(const float4*)(pb_ + 4);              \
      rBf[2] = *(const float4*)(pb_ + 8); rBf[3] = *(const float4*)(pb_ + 12);             \
    } else {                                                                               \
      int n_ = tid & 127, kq2_ = (tid >> 7) * 16;                                          \
      size_t boff_ = (size_t)(((MODE == 2 || MODE == 3) ? g * 256 : 0) + col0 + n_) * 256  \
                     + (kk) + kq2_;                                                        \
      rBh0 = *(const short8v*)&Bh_g[boff_]; rBh1 = *(const short8v*)&Bh_g[boff_ + 8];      \
      rBl0 = *(const short8v*)&Bl_g[boff_]; rBl1 = *(const short8v*)&Bl_g[boff_ + 8];      \
    }                                                                                      \
  }

template<int MODE>
__global__ __launch_bounds__(256, 2) void k_mfma(
    const u16* __restrict__ Ah_g, const u16* __restrict__ Al_g,
    const u16* __restrict__ Bh_g, const u16* __restrict__ Bl_g,
    const float* __restrict__ Bfp,
    float* __restrict__ Cf, u16* __restrict__ Ch, u16* __restrict__ Cl,
    const float* __restrict__ nrm, const float* __restrict__ dinv,
    const float* __restrict__ bias) {
  __shared__ u16 Ahs[64][LSTR], Als[64][LSTR];
  __shared__ u16 Bhs[128][LSTR], Bls[128][LSTR];
  const int tid = threadIdx.x;
  const int g = blockIdx.z, by = blockIdx.y;
  const int col0 = blockIdx.x * 128;
  const int w = tid >> 6, lane = tid & 63;
  const int lm = lane & 15, lq = lane >> 4;
  const int wr = (w >> 1) * 32, wc = (w & 1) * 64;

  float4v acc[2][4];
#pragma unroll
  for (int i = 0; i < 2; ++i)
#pragma unroll
    for (int j = 0; j < 4; ++j) acc[i][j] = (float4v)0.f;

  short8v rAh, rAl, rBh0, rBh1, rBl0, rBl1;
  float4 rBf[4];
  const int TOTAL = (MODE == 1) ? 24 : 8;

  LOAD_REGS(0, 0);
  for (int step = 0; step < TOTAL; ++step) {
    if (step) __syncthreads();
    // ---- store prefetched regs to LDS ----
    {
      int m = tid >> 2, kq = (tid & 3) * 8;
      *(short8v*)&Ahs[m][kq] = rAh;
      *(short8v*)&Als[m][kq] = rAl;
    }
    if (MODE == 1) {
      int n = tid >> 1, kq2 = (tid & 1) * 16;
      u16 hh[16], ll[16];
#pragma unroll
      for (int q = 0; q < 4; ++q) {
        split2(rBf[q].x, hh[q * 4 + 0], ll[q * 4 + 0]);
        split2(rBf[q].y, hh[q * 4 + 1], ll[q * 4 + 1]);
        split2(rBf[q].z, hh[q * 4 + 2], ll[q * 4 + 2]);
        split2(rBf[q].w, hh[q * 4 + 3], ll[q * 4 + 3]);
      }
      *(short8v*)&Bhs[n][kq2] = *(short8v*)hh; *(short8v*)&Bhs[n][kq2 + 8] = *(short8v*)(hh + 8);
      *(short8v*)&Bls[n][kq2] = *(short8v*)ll; *(short8v*)&Bls[n][kq2 + 8] = *(short8v*)(ll + 8);
    } else {
      int n = tid & 127, kq2 = (tid >> 7) * 16;
      *(short8v*)&Bhs[n][kq2] = rBh0; *(short8v*)&Bhs[n][kq2 + 8] = rBh1;
      *(short8v*)&Bls[n][kq2] = rBl0; *(short8v*)&Bls[n][kq2 + 8] = rBl1;
    }
    __syncthreads();
    // ---- prefetch next step while computing ----
    int nxt = step + 1;
    if (nxt < TOTAL) {
      int tt = nxt >> 3, kk = (nxt & 7) * 32;
      LOAD_REGS(tt, kk);
    }
    // ---- fragments + MFMA ----
    short8v ah[2], al[2], bh[4], bl[4];
#pragma unroll
    for (int i = 0; i < 2; ++i) {
      int r = wr + i * 16 + lm;
      ah[i] = *(const short8v*)&Ahs[r][lq * 8];
      al[i] = *(const short8v*)&Als[r][lq * 8];
    }
#pragma unroll
    for (int j = 0; j < 4; ++j) {
      int r = wc + j * 16 + lm;
      bh[j] = *(const short8v*)&Bhs[r][lq * 8];
      bl[j] = *(const short8v*)&Bls[r][lq * 8];
    }
#pragma unroll
    for (int i = 0; i < 2; ++i)
#pragma unroll
      for (int j = 0; j < 4; ++j) {
        acc[i][j] = __builtin_amdgcn_mfma_f32_16x16x32_bf16(ah[i], bh[j], acc[i][j], 0, 0, 0);
        acc[i][j] = __builtin_amdgcn_mfma_f32_16x16x32_bf16(ah[i], bl[j], acc[i][j], 0, 0, 0);
        acc[i][j] = __builtin_amdgcn_mfma_f32_16x16x32_bf16(al[i], bh[j], acc[i][j], 0, 0, 0);
      }
  }
  // ---- epilogues (C/D frag: col=lm, row=lq*4+reg) ----
  if (MODE == 0) {
#pragma unroll
    for (int i = 0; i < 2; ++i) {
      int gr0 = by * 64 + wr + i * 16 + lq * 4;
#pragma unroll
      for (int j = 0; j < 4; ++j) {
        int gc = col0 + wc + j * 16 + lm;
        u16 hh[4], ll[4];
#pragma unroll
        for (int r = 0; r < 4; ++r) split2(acc[i][j][r], hh[r], ll[r]);
        size_t off = (size_t)gc * 8192 + gr0;
        *(ushort4*)&Ch[off] = *(ushort4*)hh;
        *(ushort4*)&Cl[off] = *(ushort4*)ll;
      }
    }
  } else if (MODE == 1) {
#pragma unroll
    for (int i = 0; i < 2; ++i) {
      int gd0 = by * 64 + wr + i * 16 + lq * 4;
      float bs[4];
#pragma unroll
      for (int r = 0; r < 4; ++r) {
        int d = gd0 + r;
        bs[r] = bias[d] + bias[256 + d] + bias[512 + d];
      }
#pragma unroll
      for (int j = 0; j < 4; ++j) {
        int node = g * 256 + col0 + wc + j * 16 + lm;
        u16 hh[4], ll[4];
#pragma unroll
        for (int r = 0; r < 4; ++r) {
          float v = fmaxf(acc[i][j][r] + bs[r], 0.f);
          split2(v, hh[r], ll[r]);
        }
        size_t off = (size_t)node * 256 + gd0;
        *(ushort4*)&Ch[off] = *(ushort4*)hh;
        *(ushort4*)&Cl[off] = *(ushort4*)ll;
      }
    }
  } else if (MODE == 2 || MODE == 3) {
#pragma unroll
    for (int i = 0; i < 2; ++i) {
#pragma unroll
      for (int r = 0; r < 4; ++r) {
        int grow = g * 256 + by * 64 + wr + i * 16 + lq * 4 + r;
        float di = 0.f, ni = 0.f;
        if (MODE == 2) { di = dinv[grow]; ni = nrm[grow]; }
#pragma unroll
        for (int j = 0; j < 4; ++j) {
          int gcol = col0 + wc + j * 16 + lm;
          size_t ci = (size_t)grow * 256 + gcol;
          float v = acc[i][j][r];
          if (MODE == 2) {
            int gj = g * 256 + gcol;
            Cf[ci] = v * di * dinv[gj] / (ni * nrm[gj] + ZEROF);
          } else {
            Cf[ci] = 0.5f * Cf[ci] + 0.5f * (1.f / (1.f + expf(-v)));
          }
        }
      }
    }
  } else {  // MODE 4
#pragma unroll
    for (int i = 0; i < 2; ++i) {
#pragma unroll
      for (int r = 0; r < 4; ++r) {
        int grow = by * 64 + wr + i * 16 + lq * 4 + r;
#pragma unroll
        for (int j = 0; j < 4; ++j) {
          int gcol = col0 + wc + j * 16 + lm;
          u16 h, l;
          split2(acc[i][j][r], h, l);
          size_t off = (size_t)grow * 256 + gcol;
          Ch[off] = h;
          Cl[off] = l;
        }
      }
    }
  }
}

// ---------------- fused maps (rowmaps + min/max/sum normalize) ----------------
__global__ void k_maps(const float* __restrict__ Abuf, const float* __restrict__ emf,
                       const float* __restrict__ pmf, float* __restrict__ out) {
  __shared__ float sme[256], smp[256], red[256];
  const int g = blockIdx.x, tid = threadIdx.x, w = tid >> 6, lane = tid & 63;
  const int j0 = g * 256 + lane * 4;
  const float4 pmv = *(const float4*)&pmf[j0];
  const float4 emv = *(const float4*)&emf[j0];
  for (int it = 0; it < 64; ++it) {
    int nl = it * 4 + w;
    const float4 a = *(const float4*)&Abuf[((size_t)g * 256 + nl) * 256 + lane * 4];
    float me = a.x * pmv.x + a.y * pmv.y + a.z * pmv.z + a.w * pmv.w;
    float mp = a.x * emv.x + a.y * emv.y + a.z * emv.z + a.w * emv.w;
#pragma unroll
    for (int off = 32; off > 0; off >>= 1) {
      me += __shfl_down(me, off, 64);
      mp += __shfl_down(mp, off, 64);
    }
    if (lane == 0) { sme[nl] = me; smp[nl] = mp; }
  }
  __syncthreads();
  for (int which = 0; which < 2; ++which) {
    float v = which ? smp[tid] : sme[tid];
    red[tid] = v; __syncthreads();
    for (int s = 128; s > 0; s >>= 1) { if (tid < s) red[tid] = fminf(red[tid], red[tid + s]); __syncthreads(); }
    float mn = red[0]; __syncthreads();
    red[tid] = v; __syncthreads();
    for (int s = 128; s > 0; s >>= 1) { if (tid < s) red[tid] = fmaxf(red[tid], red[tid + s]); __syncthreads(); }
    float mx = red[0]; __syncthreads();
    float m = (v - mn) / (mx - mn + ZEROF);
    red[tid] = m; __syncthreads();
    for (int s = 128; s > 0; s >>= 1) { if (tid < s) red[tid] += red[tid + s]; __syncthreads(); }
    float sum = red[0]; __syncthreads();
    out[which * NND + g * 256 + tid] = m / (sum + ZEROF);
  }
}

// ---------------- launch ----------------
extern "C" void kernel_launch(void* const* d_in, const int* in_sizes, int n_in,
                              void* d_out, int out_size, void* d_ws, size_t ws_size,
                              hipStream_t stream) {
  const float* x = (const float*)d_in[0];
  const unsigned char* em_raw = (const unsigned char*)d_in[7];
  const unsigned char* pm_raw = (const unsigned char*)d_in[8];
  const float* W  = (const float*)d_in[9];
  const float* bg = (const float*)d_in[10];
  const float* T  = (const float*)d_in[11];
  float* out = (float*)d_out;
  const int E_ = in_sizes[2];
  const int E2 = 2 * E_;

  float* ws = (float*)d_ws;
  size_t o = 0;
  float* Abuf = ws + o; o += (size_t)NND * 256;           // 2M
  float* Mb3  = ws + o; o += (size_t)NGRP * 3 * 65536;    // 6.3M
  u16* Hh   = (u16*)(ws + o); o += (size_t)NND * 256 / 2; // 2M u16
  u16* Hl   = (u16*)(ws + o); o += (size_t)NND * 256 / 2;
  u16* tmph = (u16*)(ws + o); o += (size_t)NND * 256 / 2;
  u16* tmpl = (u16*)(ws + o); o += (size_t)NND * 256 / 2;
  u16* XWTh = (u16*)(ws + o); o += (size_t)768 * NND / 2; // 6.3M u16
  u16* XWTl = (u16*)(ws + o); o += (size_t)768 * NND / 2;
  u16* Wth  = (u16*)(ws + o); o += (size_t)8 * 65536 / 2;
  u16* Wtl  = (u16*)(ws + o); o += (size_t)8 * 65536 / 2;
  float* nrm  = ws + o; o += NND;
  float* dinv = ws + o; o += NND;
  float* S    = ws + o; o += 256;
  float* emf  = ws + o; o += NND;
  float* pmf  = ws + o; o += NND;
  int* edges  = (int*)(ws + o); o += (size_t)3 * E2;
  int* flags  = (int*)(ws + o); o += 16;

  // prep
  k_detect<<<1, 256, 0, stream>>>((const int*)d_in[1], em_raw, flags, S);
  int cvtTotal = 3 * E2 + 2 * NND;
  k_cvt_all<<<(cvtTotal + 255) / 256, 256, 0, stream>>>(
      (const int*)d_in[1], (const int*)d_in[3], (const int*)d_in[5],
      em_raw, pm_raw, edges, emf, pmf, E2, flags);
  k_transpose8<<<dim3(8, 8, 8), 256, 0, stream>>>(W, T, Wth, Wtl);
  k_split_x<<<NND * 256 / 8 / 256, 256, 0, stream>>>(x, Hh, Hl);
  k_norms_colsum<<<NND / 64, 256, 0, stream>>>(x, nrm, S);
  k_dinv<<<NND / 4, 256, 0, stream>>>(x, S, nrm, dinv);

  // initial A (diagonal blocks, factored rowsum)
  k_mfma<2><<<dim3(2, 4, NGRP), 256, 0, stream>>>(
      Hh, Hl, Hh, Hl, nullptr, Abuf, nullptr, nullptr, nrm, dinv, nullptr);

  const float* ew0 = (const float*)d_in[2];
  const float* ew1 = (const float*)d_in[4];
  const float* ew2 = (const float*)d_in[6];
  const size_t Mbytes = (size_t)NGRP * 3 * 65536 * sizeof(float);

  for (int l = 0; l < 2; ++l) {
    hipMemsetAsync(Mb3, 0, Mbytes, stream);
    k_edge3<<<(3 * E_ + 255) / 256, 256, 0, stream>>>(edges, ew0, ew1, ew2, Abuf, Mb3, E_, l);
    // XWT = (H @ [W0|W1|W2])^T
    k_mfma<0><<<dim3(6, 128, 1), 256, 0, stream>>>(
        Hh, Hl, Wth + (size_t)l * 768 * 256, Wtl + (size_t)l * 768 * 256,
        nullptr, nullptr, XWTh, XWTl, nullptr, nullptr, nullptr);
    // H = relu(bias + sum_t M_t @ XW_t)
    k_mfma<1><<<dim3(2, 4, NGRP), 256, 0, stream>>>(
        XWTh, XWTl, nullptr, nullptr, Mb3, nullptr, Hh, Hl, nullptr, nullptr, bg + (size_t)l * 768);
    // tmp = H @ T[l]
    k_mfma<4><<<dim3(2, 128, 1), 256, 0, stream>>>(
        Hh, Hl, Wth + (size_t)(6 + l) * 65536, Wtl + (size_t)(6 + l) * 65536,
        nullptr, nullptr, tmph, tmpl, nullptr, nullptr, nullptr);
    // A = 0.5 A + 0.5 sigmoid(tmp @ H^T)
    k_mfma<3><<<dim3(2, 4, NGRP), 256, 0, stream>>>(
        tmph, tmpl, Hh, Hl, nullptr, Abuf, nullptr, nullptr, nullptr, nullptr, nullptr);
  }

  k_maps<<<NGRP, 256, 0, stream>>>(Abuf, emf, pmf, out);
}